// Round 12
// baseline (114.645 us; speedup 1.0000x reference)
//
#include <hip/hip_runtime.h>
#include <hip/hip_bf16.h>
#include <math.h>

// Problem constants
#define NB 8      // batch
#define NC 128    // channels
#define NH 64     // height
#define NW 64     // width
#define NP 1024   // npatch (32x32)
#define TWO_SIG2 5.12f      // 2*(0.05*32)^2
#define LOG2E 1.44269504089f
#define NT 6      // candidates kept per (row, chunk, channel)

// ws layout (bytes):
//   psum : [NB][3][4cc][NP] fp32                 = 384 KB (partial exp row-sums)
//   cand : [NB*NP][3ch][4cc][6] fp32 (packed g)  = 2.25 MB
//   xd   : [NB*2][NP][NC] bf16                   = 4 MB
static const size_t PSUM_OFF_B = 0;
static const size_t CAND_OFF_B = (size_t)NB * 3 * 4 * NP * 4;
static const size_t XD_OFF_B   = CAND_OFF_B + (size_t)NB * NP * 3 * 4 * NT * 4;

typedef __bf16 bf16x8 __attribute__((ext_vector_type(8)));
typedef float f32x4 __attribute__((ext_vector_type(4)));

// Insert v into sorted-descending triple (A >= B >= C)
#define INSERT3(v, A, Bq, Cq)                          \
  {                                                    \
    const float _na = fmaxf(A, (v));                   \
    const float _nb = __builtin_amdgcn_fmed3f(A, Bq, (v)); \
    Cq = __builtin_amdgcn_fmed3f(Bq, Cq, (v));         \
    A = _na;                                           \
    Bq = _nb;                                          \
  }

// Insert v into sorted-descending quad (A >= B >= C >= D)
#define INSERT4(v, A, Bq, Cq, Dq)                      \
  {                                                    \
    const float _na = fmaxf(A, (v));                   \
    const float _nb = __builtin_amdgcn_fmed3f(A, Bq, (v)); \
    const float _nc = __builtin_amdgcn_fmed3f(Bq, Cq, (v)); \
    Dq = __builtin_amdgcn_fmed3f(Cq, Dq, (v));         \
    A = _na; Bq = _nb; Cq = _nc;                       \
  }

// pack 8-bit column index into low mantissa bits of g (keeps ordering to 2^-14)
__device__ __forceinline__ float packf(float g, unsigned idx) {
  return __uint_as_float((__float_as_uint(g) & 0xFFFFFF00u) | idx);
}

// ---------------------------------------------------------------------------
// K1: L2-normalize over channels at the two diagonal pixels of each 2x2 patch
//     and write transposed xd[b][p][n][c] (c contiguous) as bf16.
// grid (16 chunks of 64 patches, p=2, b=8), block 1024  (R8-verified)
// ---------------------------------------------------------------------------
__global__ __launch_bounds__(1024) void k1_norm(const float* __restrict__ x,
                                                __hip_bfloat16* __restrict__ xd) {
  __shared__ __align__(16) float tile[NC * 65];
  const int chunk = blockIdx.x;
  const int p = blockIdx.y;
  const int b = blockIdx.z;
  const int t = threadIdx.x;
  const int pix = t & 63;
  const int cw = t >> 6;          // 0..15
  const int nbase = chunk * 64;

  {
    const int n = nbase + pix;
    const int i = ((n >> 5) << 1) + p;   // 2r + p
    const int jf = (n & 31);             // float2 index: cols (2jf, 2jf+1)
    const float* xb = x + (size_t)b * NC * NH * NW + (size_t)i * NW;
    for (int cc = 0; cc < 8; ++cc) {
      const int c = (cc << 4) + cw;
      const float2 v2 = ((const float2*)(xb + (size_t)c * NH * NW))[jf];
      tile[c * 65 + pix] = (p == 0) ? v2.x : v2.y;
    }
  }
  __syncthreads();

  const int lane = t & 63;
  const int w = t >> 6;           // 0..15
  for (int pg = 0; pg < 4; ++pg) {
    const int pixel = (pg << 4) + w;     // each wave owns one pixel (128 channels)
    const float v0 = tile[lane * 65 + pixel];
    const float v1 = tile[(lane + 64) * 65 + pixel];
    float ss = v0 * v0 + v1 * v1;
#pragma unroll
    for (int m = 32; m >= 1; m >>= 1) ss += __shfl_xor(ss, m, 64);
    const float inv = 1.0f / fmaxf(sqrtf(ss), 1e-12f);
    __hip_bfloat16* xr = xd + ((size_t)((b * 2 + p) * NP) + nbase + pixel) * NC;
    xr[lane] = __float2bfloat16(v0 * inv);
    xr[lane + 64] = __float2bfloat16(v1 * inv);
  }
}

// ---------------------------------------------------------------------------
// K2: corr via MFMA (A-frags in registers, Bs in LDS, R8-proven layout) ->
// mask -> exp2 -> partial row sums AND per-chunk top-6 candidates.
// T14 async-split: tile sc+1's global loads issued right after tile sc's LDS
// write. __launch_bounds__(256, 2): 2 waves/EU == the grid-supplied occupancy
// (512 blocks = 2 blocks/CU), raising the VGPR budget to ~256 so the ~190
// live registers (a-frags+acc+Lc+sums+nb) FIT — R10's identical kernel ran
// under an occupancy-targeted 116-VGPR cap and spilled 47 MB to scratch.
// grid (4 colchunk, 16 rowtile, 8 b), block 256 (4 waves; wave owns 16 rows)
// ---------------------------------------------------------------------------
__global__ __launch_bounds__(256, 2) void k2_sums(const ushort* __restrict__ xd,
                                                  const float* __restrict__ alpha_p,
                                                  float* __restrict__ psum,
                                                  float* __restrict__ cand) {
  __shared__ __align__(16) __bf16 Bs[2][64 * 136];
  __shared__ float stage[64][3][NT];   // extracted candidates (4.6 KB)
  const int t = threadIdx.x;
  const float K = (*alpha_p) * LOG2E;
  const float Cm = -(LOG2E / TWO_SIG2);   // exp(-d2/TWO_SIG2) = exp2(d2*Cm)

  const int cchunk = blockIdx.x;
  const int rowtile = blockIdx.y;
  const int b = blockIdx.z;
  const int i0 = rowtile << 6;
  const int jb = cchunk << 8;

  const int wave = t >> 6;
  const int lane = t & 63;
  const int lrow = lane & 15;
  const int kq = lane >> 4;

  const __bf16* X = (const __bf16*)xd;
  const __bf16* xp0 = X + ((size_t)(b * 2 + 0) * NP) * NC;
  const __bf16* xp1 = X + ((size_t)(b * 2 + 1) * NP) * NC;

  // staging address pieces (f = it*256 + t; r = f>>4; q = f&15)
  const int sr = t >> 4;          // + it*16
  const int sq = t & 15;

  // prologue: issue A-frag loads and tile-0 B loads immediately
  bf16x8 a0[4], a1[4];
  {
    const __bf16* pa0 = xp0 + (size_t)(i0 + wave * 16 + lrow) * NC + kq * 8;
    const __bf16* pa1 = xp1 + (size_t)(i0 + wave * 16 + lrow) * NC + kq * 8;
#pragma unroll
    for (int kc = 0; kc < 4; ++kc) {
      a0[kc] = *(const bf16x8*)(pa0 + kc * 32);
      a1[kc] = *(const bf16x8*)(pa1 + kc * 32);
    }
  }
  float4 nb[8];
  {
    const float4* gb0 = (const float4*)(xd + ((size_t)(b * 2 + 0) * NP + jb) * NC);
    const float4* gb1 = (const float4*)(xd + ((size_t)(b * 2 + 1) * NP + jb) * NC);
#pragma unroll
    for (int it = 0; it < 4; ++it) {
      nb[it] = gb0[(it << 8) + t];
      nb[4 + it] = gb1[(it << 8) + t];
    }
  }

  // row geometry: rn constant across reg (n0&31 <= 28)
  const int n0 = i0 + wave * 16 + kq * 4;
  const float rnf = (float)(n0 >> 5);
  const float cn0 = (float)(n0 & 31);

  float sums[3][4];
  float Lc[3][4][4];   // per-lane sorted-4 candidate lists [ch][reg][pos]
#pragma unroll
  for (int ch = 0; ch < 3; ++ch)
#pragma unroll
    for (int reg = 0; reg < 4; ++reg) {
      sums[ch][reg] = 0.f;
#pragma unroll
      for (int q = 0; q < 4; ++q) Lc[ch][reg][q] = -3.0e38f;
    }

  for (int sc = 0; sc < 4; ++sc) {
    const int j0 = jb + (sc << 6);
    if (sc) __syncthreads();   // everyone done reading Bs tile sc-1

    // write current tile to LDS (compiler waits vmcnt for nb here)
#pragma unroll
    for (int it = 0; it < 4; ++it) {
      *(float4*)(&Bs[0][(it * 16 + sr) * 136 + sq * 8]) = nb[it];
      *(float4*)(&Bs[1][(it * 16 + sr) * 136 + sq * 8]) = nb[4 + it];
    }

    // T14: issue NEXT tile's global loads now — they fly during MFMA+epilogue
    if (sc < 3) {
      const int j0n = jb + ((sc + 1) << 6);
      const float4* gb0 = (const float4*)(xd + ((size_t)(b * 2 + 0) * NP + j0n) * NC);
      const float4* gb1 = (const float4*)(xd + ((size_t)(b * 2 + 1) * NP + j0n) * NC);
#pragma unroll
      for (int it = 0; it < 4; ++it) {
        nb[it] = gb0[(it << 8) + t];
        nb[4 + it] = gb1[(it << 8) + t];
      }
    }
    __syncthreads();   // Bs tile sc ready

    f32x4 acc[2][4];
#pragma unroll
    for (int pl = 0; pl < 2; ++pl)
#pragma unroll
      for (int ct = 0; ct < 4; ++ct)
#pragma unroll
        for (int u = 0; u < 4; ++u) acc[pl][ct][u] = 0.f;

#pragma unroll
    for (int kc = 0; kc < 4; ++kc) {
      const int kk = kc * 32 + (kq << 3);
#pragma unroll
      for (int ct = 0; ct < 4; ++ct) {
        const bf16x8 b0 = *(const bf16x8*)(&Bs[0][(ct * 16 + lrow) * 136 + kk]);
        const bf16x8 b1 = *(const bf16x8*)(&Bs[1][(ct * 16 + lrow) * 136 + kk]);
        acc[0][ct] = __builtin_amdgcn_mfma_f32_16x16x32_bf16(a0[kc], b0, acc[0][ct], 0, 0, 0);
        acc[1][ct] = __builtin_amdgcn_mfma_f32_16x16x32_bf16(a1[kc], b1, acc[1][ct], 0, 0, 0);
      }
    }

    // mask + exp2 + partial row sums + candidate inserts (hides nb loads)
#pragma unroll
    for (int ct = 0; ct < 4; ++ct) {
      const int mc = (sc << 6) + ct * 16 + lrow;   // col within chunk 0..255
      const int m = jb + mc;
      const float rmf = (float)(m >> 5);
      const float cmf = (float)(m & 31);
      const float dr = rnf - rmf;
      const float dr2 = dr * dr;
      const unsigned mcu = (unsigned)mc;
#pragma unroll
      for (int reg = 0; reg < 4; ++reg) {
        const float dc = cn0 + (float)reg - cmf;
        const float d2 = fmaf(dc, dc, dr2);
        const float em = __builtin_amdgcn_exp2f(d2 * Cm);   // exact 1 on diagonal
        const float fm2 = fmaf(-em, K, K);                  // K*(1-g); exact 0 on diag
        const float g0 = fm2 * acc[0][ct][reg];
        const float g1 = fm2 * acc[1][ct][reg];
        sums[0][reg] += __builtin_amdgcn_exp2f(g0);
        sums[1][reg] += __builtin_amdgcn_exp2f(g1);
        sums[2][reg] += __builtin_amdgcn_exp2f(0.5f * (g0 + g1));
        const float p0 = packf(g0, mcu);
        const float p1 = packf(g1, mcu);
        const float p2 = packf(g0 + g1, mcu);
        INSERT4(p0, Lc[0][reg][0], Lc[0][reg][1], Lc[0][reg][2], Lc[0][reg][3]);
        INSERT4(p1, Lc[1][reg][0], Lc[1][reg][1], Lc[1][reg][2], Lc[1][reg][3]);
        INSERT4(p2, Lc[2][reg][0], Lc[2][reg][1], Lc[2][reg][2], Lc[2][reg][3]);
      }
    }
  }

  // reduce partial sums across the 16 col-lanes (same rows)
#pragma unroll
  for (int off = 1; off < 16; off <<= 1)
#pragma unroll
    for (int ch = 0; ch < 3; ++ch)
#pragma unroll
      for (int reg = 0; reg < 4; ++reg)
        sums[ch][reg] += __shfl_xor(sums[ch][reg], off, 64);

  if (lrow == 0) {
#pragma unroll
    for (int ch = 0; ch < 3; ++ch)
#pragma unroll
      for (int reg = 0; reg < 4; ++reg) {
        const int n = i0 + wave * 16 + kq * 4 + reg;
        psum[(((size_t)b * 3 + ch) * 4 + cchunk) * NP + n] = sums[ch][reg];
      }
  }

  // cross-lane extraction: top-6 of the 16 lanes' sorted-4 lists.
  // Packed index bits make all values in a chunk distinct -> exact == test.
#pragma unroll
  for (int ch = 0; ch < 3; ++ch)
#pragma unroll
    for (int reg = 0; reg < 4; ++reg) {
      float l0 = Lc[ch][reg][0], l1 = Lc[ch][reg][1];
      float l2 = Lc[ch][reg][2], l3 = Lc[ch][reg][3];
      const int np = wave * 16 + kq * 4 + reg;
#pragma unroll
      for (int r = 0; r < NT; ++r) {
        float mx = l0;
        mx = fmaxf(mx, __shfl_xor(mx, 1, 64));
        mx = fmaxf(mx, __shfl_xor(mx, 2, 64));
        mx = fmaxf(mx, __shfl_xor(mx, 4, 64));
        mx = fmaxf(mx, __shfl_xor(mx, 8, 64));
        if (lrow == 0) stage[np][ch][r] = mx;
        const bool own = (l0 == mx);
        l0 = own ? l1 : l0;
        l1 = own ? l2 : l1;
        l2 = own ? l3 : l2;
        l3 = own ? -3.0e38f : l3;
      }
    }
  __syncthreads();

  // cooperative coalesced store of the 64x3x6 candidate block
  for (int u = t; u < 64 * 3 * NT; u += 256) {
    const int np = u / (3 * NT);
    const int rem = u - np * (3 * NT);
    const int ch = rem / NT;
    const int r = rem - ch * NT;
    cand[(((size_t)b * NP + i0 + np) * 3 + ch) * (4 * NT) + cchunk * NT + r] =
        stage[np][ch][r];
  }
}

// ---------------------------------------------------------------------------
// K5: exact finish. Build -log2(colsum) table, evaluate the 72 candidates
// per row with the exact t = c*g - log2(R[m]), top-3, scale by 1/R[n],
// scatter to output. grid (32), block 256 — one thread per (b, n).
// ---------------------------------------------------------------------------
__global__ __launch_bounds__(256) void k5_final(const float* __restrict__ cand,
                                                const float* __restrict__ psum,
                                                float* __restrict__ out) {
  __shared__ float nlR[3][NP];   // -log2(R[m]) for this b (12 KB)
  const int t = threadIdx.x;
  const int tau = blockIdx.x * 256 + t;   // 0..8191
  const int b = tau >> 10;
  const int n = tau & (NP - 1);

#pragma unroll
  for (int ch = 0; ch < 3; ++ch)
#pragma unroll
    for (int k = 0; k < 4; ++k) {
      const int m = (k << 8) + t;
      const float* pp = psum + ((size_t)b * 3 + ch) * 4 * NP + m;
      nlR[ch][m] = -__builtin_amdgcn_logf(pp[0] + pp[NP] + pp[2 * NP] + pp[3 * NP]);
    }
  __syncthreads();

  float irn[3];
#pragma unroll
  for (int ch = 0; ch < 3; ++ch) {
    const float* pp = psum + ((size_t)b * 3 + ch) * 4 * NP + n;
    irn[ch] = 1.0f / (pp[0] + pp[NP] + pp[2 * NP] + pp[3 * NP]);
  }

  float o0[3], o1[3], o2[3];
#pragma unroll
  for (int ch = 0; ch < 3; ++ch) {
    float tA = -3.0e38f, tB = -3.0e38f, tC = -3.0e38f;
    const float cf = (ch == 2) ? 1.0f : 2.0f;   // ch2 stores g0+g1 (already 2x)
    const float* cp = cand + (((size_t)b * NP + n) * 3 + ch) * (4 * NT);
#pragma unroll
    for (int cc = 0; cc < 4; ++cc)
#pragma unroll
      for (int r = 0; r < NT; ++r) {
        const float p = cp[cc * NT + r];
        const int mi = (cc << 8) | (int)(__float_as_uint(p) & 255u);
        const float tv = fmaf(cf, p, nlR[ch][mi]);
        INSERT3(tv, tA, tB, tC);
      }
    o0[ch] = __builtin_amdgcn_exp2f(tA) * irn[ch];
    o1[ch] = __builtin_amdgcn_exp2f(tB) * irn[ch];
    o2[ch] = __builtin_amdgcn_exp2f(tC) * irn[ch];
  }

  // scatter: output channel = topk RANK tt; pixel = source channel:
  //   ch0 -> (2r,2c); ch1 -> (2r+1,2c+1); ch2 -> (2r,2c+1) and (2r+1,2c)
  const int rn = n >> 5, cn = n & 31;
  float* ob = out + (size_t)b * 3 * (NH * NW);
  const int i00 = ((rn << 1) * NW) + (cn << 1);
#pragma unroll
  for (int tt = 0; tt < 3; ++tt) {
    float* op = ob + (size_t)tt * (NH * NW);
    const float r0 = (tt == 0) ? o0[0] : (tt == 1) ? o1[0] : o2[0];
    const float r1 = (tt == 0) ? o0[1] : (tt == 1) ? o1[1] : o2[1];
    const float r2 = (tt == 0) ? o0[2] : (tt == 1) ? o1[2] : o2[2];
    op[i00] = r0;            // (2r, 2c)      <- ch0 rank tt
    op[i00 + NW + 1] = r1;   // (2r+1, 2c+1)  <- ch1 rank tt
    op[i00 + 1] = r2;        // (2r, 2c+1)    <- ch2 rank tt
    op[i00 + NW] = r2;       // (2r+1, 2c)    <- ch2 rank tt
  }
}

extern "C" void kernel_launch(void* const* d_in, const int* in_sizes, int n_in,
                              void* d_out, int out_size, void* d_ws, size_t ws_size,
                              hipStream_t stream) {
  const float* x = (const float*)d_in[0];
  const float* alpha = (const float*)d_in[1];
  float* out = (float*)d_out;
  char* ws = (char*)d_ws;

  float* psum = (float*)(ws + PSUM_OFF_B);
  float* cand = (float*)(ws + CAND_OFF_B);
  __hip_bfloat16* xd = (__hip_bfloat16*)(ws + XD_OFF_B);

  k1_norm<<<dim3(16, 2, NB), 1024, 0, stream>>>(x, xd);
  k2_sums<<<dim3(4, 16, NB), 256, 0, stream>>>((const ushort*)xd, alpha, psum, cand);
  k5_final<<<dim3(32), 256, 0, stream>>>(cand, psum, out);
}

// Round 13
// 114.128 us; speedup vs baseline: 1.0045x; 1.0045x over previous
//
#include <hip/hip_runtime.h>
#include <hip/hip_bf16.h>
#include <math.h>

// Problem constants
#define NB 8      // batch
#define NC 128    // channels
#define NH 64     // height
#define NW 64     // width
#define NP 1024   // npatch (32x32)
#define TWO_SIG2 5.12f      // 2*(0.05*32)^2
#define LOG2E 1.44269504089f
#define NT 6      // candidates kept per (row, half-chunk, channel)
#define NHALF 8   // partials: 4 col-chunks x 2 wave-groups

// ws layout (bytes):
//   psum : [NB][3][NHALF][NP] fp32                 = 768 KB
//   cand : [NB*NP][3ch][NHALF][NT] fp32 (packed g) = 4.5 MB
//   xd   : [NB*2][NP][NC] bf16                     = 4 MB
static const size_t PSUM_OFF_B = 0;
static const size_t CAND_OFF_B = (size_t)NB * 3 * NHALF * NP * 4;
static const size_t XD_OFF_B   = CAND_OFF_B + (size_t)NB * NP * 3 * NHALF * NT * 4;

typedef __bf16 bf16x8 __attribute__((ext_vector_type(8)));
typedef float f32x4 __attribute__((ext_vector_type(4)));

// Insert v into sorted-descending triple (A >= B >= C)
#define INSERT3(v, A, Bq, Cq)                          \
  {                                                    \
    const float _na = fmaxf(A, (v));                   \
    const float _nb = __builtin_amdgcn_fmed3f(A, Bq, (v)); \
    Cq = __builtin_amdgcn_fmed3f(Bq, Cq, (v));         \
    A = _na;                                           \
    Bq = _nb;                                          \
  }

// Insert v into sorted-descending quad (A >= B >= C >= D)
#define INSERT4(v, A, Bq, Cq, Dq)                      \
  {                                                    \
    const float _na = fmaxf(A, (v));                   \
    const float _nb = __builtin_amdgcn_fmed3f(A, Bq, (v)); \
    const float _nc = __builtin_amdgcn_fmed3f(Bq, Cq, (v)); \
    Dq = __builtin_amdgcn_fmed3f(Cq, Dq, (v));         \
    A = _na; Bq = _nb; Cq = _nc;                       \
  }

// pack 8-bit column index into low mantissa bits of g (keeps ordering to 2^-14)
__device__ __forceinline__ float packf(float g, unsigned idx) {
  return __uint_as_float((__float_as_uint(g) & 0xFFFFFF00u) | idx);
}

// ---------------------------------------------------------------------------
// K1: L2-normalize over channels at the two diagonal pixels of each 2x2 patch
//     and write transposed xd[b][p][n][c] (c contiguous) as bf16.
// grid (16 chunks of 64 patches, p=2, b=8), block 1024  (R8-verified)
// ---------------------------------------------------------------------------
__global__ __launch_bounds__(1024) void k1_norm(const float* __restrict__ x,
                                                __hip_bfloat16* __restrict__ xd) {
  __shared__ __align__(16) float tile[NC * 65];
  const int chunk = blockIdx.x;
  const int p = blockIdx.y;
  const int b = blockIdx.z;
  const int t = threadIdx.x;
  const int pix = t & 63;
  const int cw = t >> 6;          // 0..15
  const int nbase = chunk * 64;

  {
    const int n = nbase + pix;
    const int i = ((n >> 5) << 1) + p;   // 2r + p
    const int jf = (n & 31);             // float2 index: cols (2jf, 2jf+1)
    const float* xb = x + (size_t)b * NC * NH * NW + (size_t)i * NW;
    for (int cc = 0; cc < 8; ++cc) {
      const int c = (cc << 4) + cw;
      const float2 v2 = ((const float2*)(xb + (size_t)c * NH * NW))[jf];
      tile[c * 65 + pix] = (p == 0) ? v2.x : v2.y;
    }
  }
  __syncthreads();

  const int lane = t & 63;
  const int w = t >> 6;           // 0..15
  for (int pg = 0; pg < 4; ++pg) {
    const int pixel = (pg << 4) + w;     // each wave owns one pixel (128 channels)
    const float v0 = tile[lane * 65 + pixel];
    const float v1 = tile[(lane + 64) * 65 + pixel];
    float ss = v0 * v0 + v1 * v1;
#pragma unroll
    for (int m = 32; m >= 1; m >>= 1) ss += __shfl_xor(ss, m, 64);
    const float inv = 1.0f / fmaxf(sqrtf(ss), 1e-12f);
    __hip_bfloat16* xr = xd + ((size_t)((b * 2 + p) * NP) + nbase + pixel) * NC;
    xr[lane] = __float2bfloat16(v0 * inv);
    xr[lane + 64] = __float2bfloat16(v1 * inv);
  }
}

// ---------------------------------------------------------------------------
// K2 (8-wave): corr via MFMA. Same 64x256 tile per block, but 8 waves:
// wave-group wg = wave>>2 handles ct in {2wg, 2wg+1}; row-group wr = wave&3
// owns rows wr*16+lrow. Per-wave work halves, resident waves/SIMD double
// (2 blocks/CU x 8 waves = 16 waves/CU = 4/SIMD) — attacks the measured
// latency-bound profile (R11: perfect async staging still 46us, VALU 23%).
// R8-style simple staging (transient registers, no persistent nb — the
// R10/R12 spill trap). __launch_bounds__(512,4) caps VGPR at 128.
// grid (4 colchunk, 16 rowtile, 8 b), block 512
// ---------------------------------------------------------------------------
__global__ __launch_bounds__(512, 4) void k2_sums(const ushort* __restrict__ xd,
                                                  const float* __restrict__ alpha_p,
                                                  float* __restrict__ psum,
                                                  float* __restrict__ cand) {
  __shared__ __align__(16) __bf16 Bs[2][64 * 136];
  __shared__ float stage[64][3][2][NT];   // per-group candidates (9.2 KB)
  const int t = threadIdx.x;
  const float K = (*alpha_p) * LOG2E;
  const float Cm = -(LOG2E / TWO_SIG2);   // exp(-d2/TWO_SIG2) = exp2(d2*Cm)

  const int cchunk = blockIdx.x;
  const int rowtile = blockIdx.y;
  const int b = blockIdx.z;
  const int i0 = rowtile << 6;
  const int jb = cchunk << 8;

  const int wave = t >> 6;        // 0..7
  const int lane = t & 63;
  const int lrow = lane & 15;
  const int kq = lane >> 4;
  const int wg = wave >> 2;       // col group 0/1 (ct = 2wg..2wg+1)
  const int wr = wave & 3;        // row group 0..3

  const __bf16* X = (const __bf16*)xd;
  const __bf16* xp0 = X + ((size_t)(b * 2 + 0) * NP) * NC;
  const __bf16* xp1 = X + ((size_t)(b * 2 + 1) * NP) * NC;

  // A fragments in registers: row = i0 + wr*16 + lrow, k = kq*8 + kc*32
  bf16x8 a0[4], a1[4];
  {
    const __bf16* pa0 = xp0 + (size_t)(i0 + wr * 16 + lrow) * NC + kq * 8;
    const __bf16* pa1 = xp1 + (size_t)(i0 + wr * 16 + lrow) * NC + kq * 8;
#pragma unroll
    for (int kc = 0; kc < 4; ++kc) {
      a0[kc] = *(const bf16x8*)(pa0 + kc * 32);
      a1[kc] = *(const bf16x8*)(pa1 + kc * 32);
    }
  }

  // row geometry: rn constant across reg (n0&31 <= 28)
  const int n0 = i0 + wr * 16 + kq * 4;
  const float rnf = (float)(n0 >> 5);
  const float cn0 = (float)(n0 & 31);

  float sums[3][4];
  float Lc[3][4][4];   // per-lane sorted-4 candidate lists [ch][reg][pos]
#pragma unroll
  for (int ch = 0; ch < 3; ++ch)
#pragma unroll
    for (int reg = 0; reg < 4; ++reg) {
      sums[ch][reg] = 0.f;
#pragma unroll
      for (int q = 0; q < 4; ++q) Lc[ch][reg][q] = -3.0e38f;
    }

  for (int sc = 0; sc < 4; ++sc) {
    const int j0 = jb + (sc << 6);
    if (sc) __syncthreads();   // everyone done reading Bs tile sc-1
    // 512 threads stage 64x128x2 planes: 2 float4 per thread per plane
#pragma unroll
    for (int pl = 0; pl < 2; ++pl) {
      const float4* gb = (const float4*)(xd + ((size_t)(b * 2 + pl) * NP + j0) * NC);
#pragma unroll
      for (int it = 0; it < 2; ++it) {
        const int f = (it << 9) + t;     // 0..1023
        const int r = f >> 4, q = f & 15;
        *(float4*)(&Bs[pl][r * 136 + q * 8]) = gb[f];
      }
    }
    __syncthreads();

    f32x4 acc[2][2];
#pragma unroll
    for (int pl = 0; pl < 2; ++pl)
#pragma unroll
      for (int cti = 0; cti < 2; ++cti)
#pragma unroll
        for (int u = 0; u < 4; ++u) acc[pl][cti][u] = 0.f;

#pragma unroll
    for (int kc = 0; kc < 4; ++kc) {
      const int kk = kc * 32 + (kq << 3);
#pragma unroll
      for (int cti = 0; cti < 2; ++cti) {
        const int ct = wg * 2 + cti;
        const bf16x8 b0 = *(const bf16x8*)(&Bs[0][(ct * 16 + lrow) * 136 + kk]);
        const bf16x8 b1 = *(const bf16x8*)(&Bs[1][(ct * 16 + lrow) * 136 + kk]);
        acc[0][cti] = __builtin_amdgcn_mfma_f32_16x16x32_bf16(a0[kc], b0, acc[0][cti], 0, 0, 0);
        acc[1][cti] = __builtin_amdgcn_mfma_f32_16x16x32_bf16(a1[kc], b1, acc[1][cti], 0, 0, 0);
      }
    }

    // mask + exp2 + partial row sums + candidate inserts
#pragma unroll
    for (int cti = 0; cti < 2; ++cti) {
      const int ct = wg * 2 + cti;
      const int mc = (sc << 6) + ct * 16 + lrow;   // col within chunk 0..255
      const int m = jb + mc;
      const float rmf = (float)(m >> 5);
      const float cmf = (float)(m & 31);
      const float dr = rnf - rmf;
      const float dr2 = dr * dr;
      const unsigned mcu = (unsigned)mc;
#pragma unroll
      for (int reg = 0; reg < 4; ++reg) {
        const float dc = cn0 + (float)reg - cmf;
        const float d2 = fmaf(dc, dc, dr2);
        const float em = __builtin_amdgcn_exp2f(d2 * Cm);   // exact 1 on diagonal
        const float fm2 = fmaf(-em, K, K);                  // K*(1-g); exact 0 on diag
        const float g0 = fm2 * acc[0][cti][reg];
        const float g1 = fm2 * acc[1][cti][reg];
        sums[0][reg] += __builtin_amdgcn_exp2f(g0);
        sums[1][reg] += __builtin_amdgcn_exp2f(g1);
        sums[2][reg] += __builtin_amdgcn_exp2f(0.5f * (g0 + g1));
        const float p0 = packf(g0, mcu);
        const float p1 = packf(g1, mcu);
        const float p2 = packf(g0 + g1, mcu);
        INSERT4(p0, Lc[0][reg][0], Lc[0][reg][1], Lc[0][reg][2], Lc[0][reg][3]);
        INSERT4(p1, Lc[1][reg][0], Lc[1][reg][1], Lc[1][reg][2], Lc[1][reg][3]);
        INSERT4(p2, Lc[2][reg][0], Lc[2][reg][1], Lc[2][reg][2], Lc[2][reg][3]);
      }
    }
  }

  // reduce partial sums across the 16 col-lanes (same rows, this group's cols)
#pragma unroll
  for (int off = 1; off < 16; off <<= 1)
#pragma unroll
    for (int ch = 0; ch < 3; ++ch)
#pragma unroll
      for (int reg = 0; reg < 4; ++reg)
        sums[ch][reg] += __shfl_xor(sums[ch][reg], off, 64);

  if (lrow == 0) {
#pragma unroll
    for (int ch = 0; ch < 3; ++ch)
#pragma unroll
      for (int reg = 0; reg < 4; ++reg) {
        const int n = i0 + wr * 16 + kq * 4 + reg;
        psum[(((size_t)b * 3 + ch) * NHALF + cchunk * 2 + wg) * NP + n] = sums[ch][reg];
      }
  }

  // cross-lane extraction: top-6 of the 16 lanes' sorted-4 lists (per group).
#pragma unroll
  for (int ch = 0; ch < 3; ++ch)
#pragma unroll
    for (int reg = 0; reg < 4; ++reg) {
      float l0 = Lc[ch][reg][0], l1 = Lc[ch][reg][1];
      float l2 = Lc[ch][reg][2], l3 = Lc[ch][reg][3];
      const int np = wr * 16 + kq * 4 + reg;
#pragma unroll
      for (int r = 0; r < NT; ++r) {
        float mx = l0;
        mx = fmaxf(mx, __shfl_xor(mx, 1, 64));
        mx = fmaxf(mx, __shfl_xor(mx, 2, 64));
        mx = fmaxf(mx, __shfl_xor(mx, 4, 64));
        mx = fmaxf(mx, __shfl_xor(mx, 8, 64));
        if (lrow == 0) stage[np][ch][wg][r] = mx;
        const bool own = (l0 == mx);
        l0 = own ? l1 : l0;
        l1 = own ? l2 : l1;
        l2 = own ? l3 : l2;
        l3 = own ? -3.0e38f : l3;
      }
    }
  __syncthreads();

  // cooperative coalesced store of the 64x3x2x6 candidate block
  for (int u = t; u < 64 * 3 * 2 * NT; u += 512) {
    const int np = u / (3 * 2 * NT);
    const int rem = u - np * (3 * 2 * NT);
    const int ch = rem / (2 * NT);
    const int rem2 = rem - ch * (2 * NT);
    const int h = rem2 / NT;
    const int r = rem2 - h * NT;
    cand[((((size_t)b * NP + i0 + np) * 3 + ch) * NHALF + cchunk * 2 + h) * NT + r] =
        stage[np][ch][h][r];
  }
}

// ---------------------------------------------------------------------------
// K5: exact finish. Build -log2(colsum) table, evaluate the 144 candidates
// per row with the exact t = c*g - log2(R[m]), top-3, scale by 1/R[n],
// scatter to output. grid (32), block 256 — one thread per (b, n).
// ---------------------------------------------------------------------------
__global__ __launch_bounds__(256) void k5_final(const float* __restrict__ cand,
                                                const float* __restrict__ psum,
                                                float* __restrict__ out) {
  __shared__ float nlR[3][NP];   // -log2(R[m]) for this b (12 KB)
  const int t = threadIdx.x;
  const int tau = blockIdx.x * 256 + t;   // 0..8191
  const int b = tau >> 10;
  const int n = tau & (NP - 1);

#pragma unroll
  for (int ch = 0; ch < 3; ++ch)
#pragma unroll
    for (int k = 0; k < 4; ++k) {
      const int m = (k << 8) + t;
      const float* pp = psum + ((size_t)b * 3 + ch) * NHALF * NP + m;
      float s = 0.f;
#pragma unroll
      for (int i = 0; i < NHALF; ++i) s += pp[i * NP];
      nlR[ch][m] = -__builtin_amdgcn_logf(s);
    }
  __syncthreads();

  float irn[3];
#pragma unroll
  for (int ch = 0; ch < 3; ++ch) {
    const float* pp = psum + ((size_t)b * 3 + ch) * NHALF * NP + n;
    float s = 0.f;
#pragma unroll
    for (int i = 0; i < NHALF; ++i) s += pp[i * NP];
    irn[ch] = 1.0f / s;
  }

  float o0[3], o1[3], o2[3];
#pragma unroll
  for (int ch = 0; ch < 3; ++ch) {
    float tA = -3.0e38f, tB = -3.0e38f, tC = -3.0e38f;
    const float cf = (ch == 2) ? 1.0f : 2.0f;   // ch2 stores g0+g1 (already 2x)
    const float* cp = cand + (((size_t)b * NP + n) * 3 + ch) * (NHALF * NT);
#pragma unroll
    for (int h = 0; h < NHALF; ++h)
#pragma unroll
      for (int r = 0; r < NT; ++r) {
        const float p = cp[h * NT + r];
        const int mi = ((h >> 1) << 8) | (int)(__float_as_uint(p) & 255u);
        const float tv = fmaf(cf, p, nlR[ch][mi]);
        INSERT3(tv, tA, tB, tC);
      }
    o0[ch] = __builtin_amdgcn_exp2f(tA) * irn[ch];
    o1[ch] = __builtin_amdgcn_exp2f(tB) * irn[ch];
    o2[ch] = __builtin_amdgcn_exp2f(tC) * irn[ch];
  }

  // scatter: output channel = topk RANK tt; pixel = source channel:
  //   ch0 -> (2r,2c); ch1 -> (2r+1,2c+1); ch2 -> (2r,2c+1) and (2r+1,2c)
  const int rn = n >> 5, cn = n & 31;
  float* ob = out + (size_t)b * 3 * (NH * NW);
  const int i00 = ((rn << 1) * NW) + (cn << 1);
#pragma unroll
  for (int tt = 0; tt < 3; ++tt) {
    float* op = ob + (size_t)tt * (NH * NW);
    const float r0 = (tt == 0) ? o0[0] : (tt == 1) ? o1[0] : o2[0];
    const float r1 = (tt == 0) ? o0[1] : (tt == 1) ? o1[1] : o2[1];
    const float r2 = (tt == 0) ? o0[2] : (tt == 1) ? o1[2] : o2[2];
    op[i00] = r0;            // (2r, 2c)      <- ch0 rank tt
    op[i00 + NW + 1] = r1;   // (2r+1, 2c+1)  <- ch1 rank tt
    op[i00 + 1] = r2;        // (2r, 2c+1)    <- ch2 rank tt
    op[i00 + NW] = r2;       // (2r+1, 2c)    <- ch2 rank tt
  }
}

extern "C" void kernel_launch(void* const* d_in, const int* in_sizes, int n_in,
                              void* d_out, int out_size, void* d_ws, size_t ws_size,
                              hipStream_t stream) {
  const float* x = (const float*)d_in[0];
  const float* alpha = (const float*)d_in[1];
  float* out = (float*)d_out;
  char* ws = (char*)d_ws;

  float* psum = (float*)(ws + PSUM_OFF_B);
  float* cand = (float*)(ws + CAND_OFF_B);
  __hip_bfloat16* xd = (__hip_bfloat16*)(ws + XD_OFF_B);

  k1_norm<<<dim3(16, 2, NB), 1024, 0, stream>>>(x, xd);
  k2_sums<<<dim3(4, 16, NB), 512, 0, stream>>>((const ushort*)xd, alpha, psum, cand);
  k5_final<<<dim3(32), 256, 0, stream>>>(cand, psum, out);
}